// Round 8
// baseline (3938.825 us; speedup 1.0000x reference)
//
#include <hip/hip_runtime.h>
#include <hip/hip_bf16.h>
#include <math.h>

#define L_   3
#define D_   256
#define H_   8
#define DFF_ 1024
#define DEP_ 40
#define B_   8
#define S_   512
#define DK_  32
#define NEG_ (-1e18f)
#define TK3  32   // attn key-tile

typedef __attribute__((ext_vector_type(8))) short    s16x8;
typedef __attribute__((ext_vector_type(8))) _Float16 f16x8;
typedef __attribute__((ext_vector_type(4))) float    f32x4;

__device__ __forceinline__ short f2h(float f) {
    union { _Float16 h; short s; } u;
    u.h = (_Float16)f;              // RN conversion
    return u.s;
}

// ---------------------------------------------------------------------------
// Elementwise copy (src -> x), float4 vectorized
// ---------------------------------------------------------------------------
__global__ void copy_kernel(const float4* __restrict__ in, float4* __restrict__ out, int n4) {
    int i = blockIdx.x * blockDim.x + threadIdx.x;
    if (i < n4) out[i] = in[i];
}

__device__ __forceinline__ float dot4(float4 a, float4 b) {
    return a.x * b.x + a.y * b.y + a.z * b.z + a.w * b.w;
}

// ---------------------------------------------------------------------------
// Weight transpose-convert: in [L][K][N] fp32 -> out [L][N][K] fp16.
// ---------------------------------------------------------------------------
__global__ __launch_bounds__(256)
void wconv(const float* __restrict__ in, short* __restrict__ out, int K, int N)
{
    __shared__ float t[32][33];
    const size_t l = blockIdx.z;
    in  += l * (size_t)K * N;
    out += l * (size_t)K * N;
    int n0 = blockIdx.x * 32, k0 = blockIdx.y * 32;
    int tx = threadIdx.x & 31, ty = threadIdx.x >> 5;    // 32 x 8
    #pragma unroll
    for (int r = 0; r < 32; r += 8)
        t[ty + r][tx] = in[(size_t)(k0 + ty + r) * N + n0 + tx];
    __syncthreads();
    #pragma unroll
    for (int r = 0; r < 32; r += 8)
        out[(size_t)(n0 + ty + r) * K + k0 + tx] = f2h(t[tx][ty + r]);
}

// ---------------------------------------------------------------------------
// fp16 MFMA GEMM, double-buffered LDS (2-phase: issue loads -> MFMA -> write).
// (unchanged from the verified round-3 kernel)
// ---------------------------------------------------------------------------
template<bool QKV, bool RELU, bool AHALF, bool OUTHF>
__global__ __launch_bounds__(256)
void gemm_mfma(const void* __restrict__ Ap,
               const short* __restrict__ W0, const short* __restrict__ W1,
               const short* __restrict__ W2,
               const float* __restrict__ b0, const float* __restrict__ b1,
               const float* __restrict__ b2,
               const float* __restrict__ resid,
               float* __restrict__ C0, float* __restrict__ C1,
               float* __restrict__ C2,
               short* __restrict__ Chf,
               int M, int N, int K, float scale)
{
    __shared__ short As[2][64 * 32];   // [buf][m][k] fp16
    __shared__ short Bs[2][64 * 32];   // [buf][n][k] fp16

    const int bm = blockIdx.y * 64;
    int bn = blockIdx.x * 64;
    int sel = 0;
    if (QKV) { sel = bn >> 8; bn &= 255; }
    const short* Wt   = QKV ? (sel == 0 ? W0 : (sel == 1 ? W1 : W2)) : W0;
    const float* bias = QKV ? (sel == 0 ? b0 : (sel == 1 ? b1 : b2)) : b0;
    float*       C    = QKV ? (sel == 0 ? C0 : (sel == 1 ? C1 : C2)) : C0;
    const float  scl  = (QKV && sel > 0) ? 1.f : scale;
    const int    ldc  = QKV ? 256 : N;

    const int tid  = threadIdx.x;
    const int row  = tid >> 2;            // 0..63 (staging row)
    const int kq   = (tid & 3) * 8;       // 0,8,16,24
    const int wid  = tid >> 6, lane = tid & 63;
    const int wm   = wid >> 1, wn = wid & 1;
    const int lr   = lane & 15, lk = (lane >> 4) * 8;

    const float* Af = (const float*)Ap;
    const short* Ah = (const short*)Ap;
    const size_t aoff = (size_t)(bm + row) * K + kq;   // + k0
    const size_t boff = (size_t)(bn + row) * K + kq;   // + k0
    const int    lofs = row * 32 + kq;

    f32x4 acc00 = {0.f, 0.f, 0.f, 0.f};
    f32x4 acc01 = acc00, acc10 = acc00, acc11 = acc00;

    // prologue: stage tile 0 into buffer 0
    {
        s16x8 ha;
        if (AHALF) {
            ha = *(const s16x8*)&Ah[aoff];
        } else {
            float4 p0 = *(const float4*)&Af[aoff];
            float4 p1 = *(const float4*)&Af[aoff + 4];
            ha[0] = f2h(p0.x); ha[1] = f2h(p0.y); ha[2] = f2h(p0.z); ha[3] = f2h(p0.w);
            ha[4] = f2h(p1.x); ha[5] = f2h(p1.y); ha[6] = f2h(p1.z); ha[7] = f2h(p1.w);
        }
        *(s16x8*)&As[0][lofs] = ha;
        *(s16x8*)&Bs[0][lofs] = *(const s16x8*)&Wt[boff];
    }

    const int nt = K >> 5;
    for (int t = 0; t < nt; ++t) {
        const int buf = t & 1;
        __syncthreads();                  // staged buf visible; buf^1 free
        float4 p0, p1; s16x8 ha, hb;
        const bool pf = (t + 1 < nt);
        if (pf) {
            const int k0 = (t + 1) << 5;
            if (AHALF) {
                ha = *(const s16x8*)&Ah[aoff + k0];
            } else {
                p0 = *(const float4*)&Af[aoff + k0];
                p1 = *(const float4*)&Af[aoff + k0 + 4];
            }
            hb = *(const s16x8*)&Wt[boff + k0];
        }
        f16x8 a0 = *(const f16x8*)&As[buf][(wm * 32 + lr) * 32 + lk];
        f16x8 a1 = *(const f16x8*)&As[buf][(wm * 32 + 16 + lr) * 32 + lk];
        f16x8 v0 = *(const f16x8*)&Bs[buf][(wn * 32 + lr) * 32 + lk];
        f16x8 v1 = *(const f16x8*)&Bs[buf][(wn * 32 + 16 + lr) * 32 + lk];
        acc00 = __builtin_amdgcn_mfma_f32_16x16x32_f16(a0, v0, acc00, 0, 0, 0);
        acc01 = __builtin_amdgcn_mfma_f32_16x16x32_f16(a0, v1, acc01, 0, 0, 0);
        acc10 = __builtin_amdgcn_mfma_f32_16x16x32_f16(a1, v0, acc10, 0, 0, 0);
        acc11 = __builtin_amdgcn_mfma_f32_16x16x32_f16(a1, v1, acc11, 0, 0, 0);
        if (pf) {
            if (!AHALF) {
                ha[0] = f2h(p0.x); ha[1] = f2h(p0.y); ha[2] = f2h(p0.z); ha[3] = f2h(p0.w);
                ha[4] = f2h(p1.x); ha[5] = f2h(p1.y); ha[6] = f2h(p1.z); ha[7] = f2h(p1.w);
            }
            *(s16x8*)&As[buf ^ 1][lofs] = ha;
            *(s16x8*)&Bs[buf ^ 1][lofs] = hb;
        }
    }

    f32x4 accs[2][2] = {{acc00, acc01}, {acc10, acc11}};
    #pragma unroll
    for (int fm = 0; fm < 2; ++fm) {
        #pragma unroll
        for (int fn = 0; fn < 2; ++fn) {
            #pragma unroll
            for (int j = 0; j < 4; ++j) {
                int m = bm + wm * 32 + fm * 16 + (lane >> 4) * 4 + j;
                int n = bn + wn * 32 + fn * 16 + lr;
                float v = (accs[fm][fn][j] + bias[n]) * scl;
                if (resid) v += resid[(size_t)m * ldc + n];
                if (RELU)  v = fmaxf(v, 0.f);
                if (OUTHF) Chf[(size_t)m * ldc + n] = f2h(v);
                else       C[(size_t)m * ldc + n]   = v;
            }
        }
    }
}

// ---------------------------------------------------------------------------
// Fused structure-aware attention v4c: latency-bound fix + nt streaming.
//  - structure tiles: prefetch depth 2, TRIPLE-buffered LDS (issue t+2 loads
//    into regs; write t+1's regs (issued one full tile ago) to LDS; compute t)
//  - structure/mask loads are NON-TEMPORAL via ext_vector f32x4 (clang's
//    builtin rejects HIP_vector_type): zero-reuse stream must not evict the
//    batch's K/V (1 MB, L2-resident per XCD thanks to the swizzle)
//  - wqk read from LDS per tile (broadcast, conflict-free) instead of 40 VGPRs
//  - XCD swizzle (batch == bid&7) + deferred alpha-rescale kept from v3
// ---------------------------------------------------------------------------
__global__ __launch_bounds__(256, 4)
void attn_kernel(const float* __restrict__ qb,   // [B,S,D] pre-scaled 1/sqrt(dk)
                 const float* __restrict__ kb,
                 const float* __restrict__ vb,
                 const float* __restrict__ structure, // [B,S,S,DEP]
                 const int*   __restrict__ mask,      // [B,S,S]
                 const int*   __restrict__ kpm,       // [B,S]
                 const float* __restrict__ Wsk, const float* __restrict__ bsk,
                 const float* __restrict__ Wsv, const float* __restrict__ bsv,
                 float* __restrict__ ctx)
{
    __shared__ float q_s[D_];
    __shared__ float wqk_s[H_][44];
    __shared__ float hb_s[H_];
    __shared__ float st_s[3][TK3][44];   // rows 16B-aligned (44*4=176)
    __shared__ float dead_s[3][TK3];     // additive 0 / -1e18
    __shared__ float sc_s[H_][TK3];

    // XCD swizzle: consecutive blockIdx round-robin XCDs; make batch == bid&7
    const int b   = blockIdx.x & 7;
    const int qi  = blockIdx.x >> 3;
    const int tid = threadIdx.x;
    const int h    = tid >> 5;
    const int lane = tid & 31;

    q_s[tid] = qb[((size_t)b * S_ + qi) * D_ + tid];
    __syncthreads();

    for (int p = tid; p < H_ * DEP_; p += 256) {
        int hh = p / DEP_, dep = p - hh * DEP_;
        const float4* wr = (const float4*)(Wsk + dep * DK_);
        const float4* qr = (const float4*)(q_s + hh * DK_);
        float s = 0.f;
        #pragma unroll
        for (int c = 0; c < 8; ++c) s += dot4(qr[c], wr[c]);
        wqk_s[hh][dep] = s;
    }
    if (tid < H_) {
        const float4* qr = (const float4*)(q_s + tid * DK_);
        const float4* br = (const float4*)bsk;
        float s = 0.f;
        #pragma unroll
        for (int c = 0; c < 8; ++c) s += dot4(qr[c], br[c]);
        hb_s[tid] = s;
    }
    __syncthreads();

    const float* kbase = kb + (size_t)b * S_ * D_;
    const float* vbase = vb + (size_t)b * S_ * D_ + tid;
    const float* strow = structure + (size_t)(b * S_ + qi) * S_ * DEP_;
    const int*   mrow  = mask + (size_t)(b * S_ + qi) * S_;
    const int*   krow  = kpm + (size_t)b * S_;

    // per-thread staging coordinates (320 float4-chunks per 32-key tile)
    const int kk0 = tid / 10, d40 = tid - kk0 * 10;         // chunk tid
    const int c1  = tid + 256;
    const int kk1 = c1 / 10,  d41 = c1 - kk1 * 10;          // chunk tid+256
    const bool has2 = (tid < 64);

    const int nt = S_ / TK3;   // 16

    // prologue: tile 0 -> LDS buf0 directly; tile 1 -> registers (r1)
    {
        *(f32x4*)&st_s[0][kk0][d40 * 4] =
            __builtin_nontemporal_load((const f32x4*)&strow[(size_t)kk0 * DEP_ + d40 * 4]);
        if (has2)
            *(f32x4*)&st_s[0][kk1][d41 * 4] =
                __builtin_nontemporal_load((const f32x4*)&strow[(size_t)kk1 * DEP_ + d41 * 4]);
        if (tid < TK3)
            dead_s[0][tid] =
                (__builtin_nontemporal_load(&mrow[tid]) == 0 || krow[tid] == 0) ? NEG_ : 0.f;
    }
    f32x4 r1a = {0.f, 0.f, 0.f, 0.f}, r1b = r1a;
    int m1 = 1, p1 = 1;
    {
        const float* s1 = strow + (size_t)TK3 * DEP_;
        r1a = __builtin_nontemporal_load((const f32x4*)&s1[(size_t)kk0 * DEP_ + d40 * 4]);
        if (has2) r1b = __builtin_nontemporal_load((const f32x4*)&s1[(size_t)kk1 * DEP_ + d41 * 4]);
        if (tid < TK3) { m1 = __builtin_nontemporal_load(&mrow[TK3 + tid]); p1 = krow[TK3 + tid]; }
    }

    float m_run = -INFINITY, l_run = 0.f, vacc = 0.f;
    float4 ps_r[10];
    #pragma unroll
    for (int c = 0; c < 10; ++c) ps_r[c] = make_float4(0.f, 0.f, 0.f, 0.f);

    const float4* qp  = (const float4*)(q_s + h * DK_);
    const float4* wq4 = (const float4*)&wqk_s[h][0];

    for (int t = 0; t < nt; ++t) {
        const int buf = t % 3;
        const int k0  = t * TK3;
        __syncthreads();                 // buf (written last iter) now visible
        // issue tile t+2 loads into regs (HBM latency hides under 2 tiles)
        f32x4 r2a = {0.f, 0.f, 0.f, 0.f}, r2b = r2a;
        int m2 = 1, p2 = 1;
        if (t + 2 < nt) {
            const float* s2 = strow + (size_t)(t + 2) * TK3 * DEP_;
            r2a = __builtin_nontemporal_load((const f32x4*)&s2[(size_t)kk0 * DEP_ + d40 * 4]);
            if (has2) r2b = __builtin_nontemporal_load((const f32x4*)&s2[(size_t)kk1 * DEP_ + d41 * 4]);
            if (tid < TK3) {
                m2 = __builtin_nontemporal_load(&mrow[(t + 2) * TK3 + tid]);
                p2 = krow[(t + 2) * TK3 + tid];
            }
        }
        // write tile t+1 (loaded a full tile ago) into buffer (t+1)%3
        if (t + 1 < nt) {
            const int wb = (t + 1) % 3;
            *(f32x4*)&st_s[wb][kk0][d40 * 4] = r1a;
            if (has2) *(f32x4*)&st_s[wb][kk1][d41 * 4] = r1b;
            if (tid < TK3) dead_s[wb][tid] = (m1 == 0 || p1 == 0) ? NEG_ : 0.f;
        }
        // ---- compute tile t ----
        const int key = k0 + lane;
        const float4* kp = (const float4*)(kbase + (size_t)key * D_ + h * DK_);
        float kq = 0.f;
        #pragma unroll
        for (int c = 0; c < 8; ++c) kq += dot4(qp[c], kp[c]);
        const float4* sp = (const float4*)&st_s[buf][lane][0];
        float bias = hb_s[h];
        #pragma unroll
        for (int c = 0; c < 10; ++c) bias += dot4(sp[c], wq4[c]);
        float sc = kq + bias + dead_s[buf][lane];
        float tm = sc;
        #pragma unroll
        for (int off = 16; off; off >>= 1) tm = fmaxf(tm, __shfl_xor(tm, off));
        float m_new = fmaxf(m_run, tm);
        float e = __expf(sc - m_new);
        float psum = e;
        #pragma unroll
        for (int off = 16; off; off >>= 1) psum += __shfl_xor(psum, off);
        // deferred rescale: skip whole pass unless the running max grew
        if (m_new > m_run) {
            float alpha = __expf(m_run - m_new);
            l_run *= alpha;
            vacc  *= alpha;
            #pragma unroll
            for (int c = 0; c < 10; ++c) {
                ps_r[c].x *= alpha; ps_r[c].y *= alpha;
                ps_r[c].z *= alpha; ps_r[c].w *= alpha;
            }
            m_run = m_new;
        }
        l_run += psum;
        sc_s[h][lane] = e;
        #pragma unroll
        for (int c = 0; c < 10; ++c) {
            float4 sv = sp[c];
            ps_r[c].x += e * sv.x;
            ps_r[c].y += e * sv.y;
            ps_r[c].z += e * sv.z;
            ps_r[c].w += e * sv.w;
        }
        #pragma unroll 8
        for (int k = 0; k < TK3; ++k) {
            vacc += sc_s[h][k] * vbase[(size_t)(k0 + k) * D_];
        }
        // rotate prefetch registers
        r1a = r2a; r1b = r2b; m1 = m2; p1 = p2;
    }

    float* pf = (float*)ps_r;
    #pragma unroll
    for (int j = 0; j < DEP_; ++j) {
        float v = pf[j];
        #pragma unroll
        for (int off = 16; off; off >>= 1) v += __shfl_xor(v, off);
        pf[j] = v;
    }
    float sv = 0.f;
    #pragma unroll
    for (int j = 0; j < DEP_; ++j) sv += pf[j] * Wsv[j * DK_ + lane];
    float invl = 1.f / l_run;
    ctx[((size_t)b * S_ + qi) * D_ + tid] = (vacc + sv) * invl + bsv[lane];
}

// ---------------------------------------------------------------------------
// LayerNorm over last dim (256). One block per row.
// ---------------------------------------------------------------------------
__global__ __launch_bounds__(256)
void ln_kernel(const float* __restrict__ x, const float* __restrict__ g,
               const float* __restrict__ b, float* __restrict__ out)
{
    int row = blockIdx.x, tid = threadIdx.x;
    float v = x[(size_t)row * D_ + tid];
    float s = v, ss = v * v;
    #pragma unroll
    for (int off = 32; off; off >>= 1) {
        s  += __shfl_xor(s, off);
        ss += __shfl_xor(ss, off);
    }
    __shared__ float rs[4], rss[4];
    int wid = tid >> 6, lane = tid & 63;
    if (lane == 0) { rs[wid] = s; rss[wid] = ss; }
    __syncthreads();
    float sum  = rs[0] + rs[1] + rs[2] + rs[3];
    float ssum = rss[0] + rss[1] + rss[2] + rss[3];
    float mean = sum * (1.f / D_);
    float var  = ssum * (1.f / D_) - mean * mean;
    out[(size_t)row * D_ + tid] = (v - mean) * rsqrtf(var + 1e-6f) * g[tid] + b[tid];
}

// ---------------------------------------------------------------------------
extern "C" void kernel_launch(void* const* d_in, const int* in_sizes, int n_in,
                              void* d_out, int out_size, void* d_ws, size_t ws_size,
                              hipStream_t stream)
{
    (void)in_sizes; (void)n_in; (void)out_size; (void)ws_size;
    const float* src       = (const float*)d_in[0];
    const int*   mask      = (const int*)  d_in[1];
    const int*   kpm       = (const int*)  d_in[2];
    const float* structure = (const float*)d_in[3];
    const float* Wq  = (const float*)d_in[4];  const float* bq  = (const float*)d_in[5];
    const float* Wk  = (const float*)d_in[6];  const float* bk  = (const float*)d_in[7];
    const float* Wv  = (const float*)d_in[8];  const float* bv  = (const float*)d_in[9];
    const float* Wo  = (const float*)d_in[10]; const float* bo  = (const float*)d_in[11];
    const float* Wsk = (const float*)d_in[12]; const float* bsk = (const float*)d_in[13];
    const float* Wsv = (const float*)d_in[14]; const float* bsv = (const float*)d_in[15];
    const float* ln1g = (const float*)d_in[16]; const float* ln1b = (const float*)d_in[17];
    const float* Wf1 = (const float*)d_in[18]; const float* bf1 = (const float*)d_in[19];
    const float* Wf2 = (const float*)d_in[20]; const float* bf2 = (const float*)d_in[21];
    const float* lnfg = (const float*)d_in[22]; const float* lnfb = (const float*)d_in[23];

    const int M = B_ * S_;                 // 4096
    const size_t NB = (size_t)M * D_;      // 1M floats = 4 MB
    float* ws   = (float*)d_ws;
    float* x    = ws;
    float* qb   = ws + 1 * NB;
    float* kb2  = ws + 2 * NB;
    float* vb2  = ws + 3 * NB;
    float* ctx  = ws + 4 * NB;
    float* outb = ws + 5 * NB;
    float* hln  = ws + 6 * NB;
    short* f1hf = (short*)(ws + 7 * NB);   // M x DFF fp16 = 8 MB (ends at 9*NB)
    short* wq_t  = (short*)(ws + 9 * NB);  // [L][D][D] fp16 (W^T per layer)
    short* wk_t  = wq_t  + (size_t)L_ * D_ * D_;
    short* wv_t  = wk_t  + (size_t)L_ * D_ * D_;
    short* wo_t  = wv_t  + (size_t)L_ * D_ * D_;
    short* wf1_t = wo_t  + (size_t)L_ * D_ * D_;    // [L][DFF][D]
    short* wf2_t = wf1_t + (size_t)L_ * D_ * DFF_;  // [L][D][DFF]

    copy_kernel<<<1024, 256, 0, stream>>>((const float4*)src, (float4*)x, (int)(NB / 4));

    // one-time (per call) weight transpose-convert to fp16 [N][K]
    wconv<<<dim3(D_ / 32, D_ / 32, L_), 256, 0, stream>>>(Wq, wq_t, D_, D_);
    wconv<<<dim3(D_ / 32, D_ / 32, L_), 256, 0, stream>>>(Wk, wk_t, D_, D_);
    wconv<<<dim3(D_ / 32, D_ / 32, L_), 256, 0, stream>>>(Wv, wv_t, D_, D_);
    wconv<<<dim3(D_ / 32, D_ / 32, L_), 256, 0, stream>>>(Wo, wo_t, D_, D_);
    wconv<<<dim3(DFF_ / 32, D_ / 32, L_), 256, 0, stream>>>(Wf1, wf1_t, D_, DFF_);
    wconv<<<dim3(D_ / 32, DFF_ / 32, L_), 256, 0, stream>>>(Wf2, wf2_t, DFF_, D_);

    const float qscale = 0.17677669529663689f; // 1/sqrt(32)
    for (int i = 0; i < L_; ++i) {
        const size_t od = (size_t)i * D_ * D_;
        const size_t of = (size_t)i * D_ * DFF_;
        // fused QKV (N=768 logical -> 3 separate [M,256] outputs)
        gemm_mfma<true, false, false, false><<<dim3(12, 64), 256, 0, stream>>>(
            x, wq_t + od, wk_t + od, wv_t + od,
            bq + i * D_, bk + i * D_, bv + i * D_, nullptr,
            qb, kb2, vb2, nullptr, M, 768, D_, qscale);
        attn_kernel<<<B_ * S_, 256, 0, stream>>>(
            qb, kb2, vb2, structure, mask, kpm,
            Wsk + (size_t)i * DEP_ * DK_, bsk + i * DK_,
            Wsv + (size_t)i * DEP_ * DK_, bsv + i * DK_, ctx);
        gemm_mfma<false, false, false, false><<<dim3(4, 64), 256, 0, stream>>>(
            ctx, wo_t + od, wo_t + od, wo_t + od,
            bo + i * D_, nullptr, nullptr, x,
            outb, nullptr, nullptr, nullptr, M, D_, D_, 1.f);
        ln_kernel<<<M, 256, 0, stream>>>(outb, ln1g + i * D_, ln1b + i * D_, hln);
        gemm_mfma<false, true, false, true><<<dim3(16, 64), 256, 0, stream>>>(
            hln, wf1_t + of, wf1_t + of, wf1_t + of,
            bf1 + i * DFF_, nullptr, nullptr, nullptr,
            nullptr, nullptr, nullptr, f1hf, M, DFF_, D_, 1.f);
        gemm_mfma<false, false, true, false><<<dim3(4, 64), 256, 0, stream>>>(
            f1hf, wf2_t + of, wf2_t + of, wf2_t + of,
            bf2 + i * D_, nullptr, nullptr, outb,
            x, nullptr, nullptr, nullptr, M, D_, DFF_, 1.f);
    }
    ln_kernel<<<M, 256, 0, stream>>>(x, lnfg, lnfb, (float*)d_out);
}

// Round 9
// 2245.324 us; speedup vs baseline: 1.7542x; 1.7542x over previous
//
#include <hip/hip_runtime.h>
#include <hip/hip_bf16.h>
#include <math.h>

#define L_   3
#define D_   256
#define H_   8
#define DFF_ 1024
#define DEP_ 40
#define B_   8
#define S_   512
#define DK_  32
#define NEG_ (-1e18f)
#define TK3  32   // attn key-tile

typedef __attribute__((ext_vector_type(8))) short    s16x8;
typedef __attribute__((ext_vector_type(8))) _Float16 f16x8;
typedef __attribute__((ext_vector_type(4))) float    f32x4;

__device__ __forceinline__ short f2h(float f) {
    union { _Float16 h; short s; } u;
    u.h = (_Float16)f;              // RN conversion
    return u.s;
}

// ---------------------------------------------------------------------------
// Elementwise copy (src -> x), float4 vectorized
// ---------------------------------------------------------------------------
__global__ void copy_kernel(const float4* __restrict__ in, float4* __restrict__ out, int n4) {
    int i = blockIdx.x * blockDim.x + threadIdx.x;
    if (i < n4) out[i] = in[i];
}

__device__ __forceinline__ float dot4(float4 a, float4 b) {
    return a.x * b.x + a.y * b.y + a.z * b.z + a.w * b.w;
}

// ---------------------------------------------------------------------------
// Weight transpose-convert: in [L][K][N] fp32 -> out [L][N][K] fp16.
// ---------------------------------------------------------------------------
__global__ __launch_bounds__(256)
void wconv(const float* __restrict__ in, short* __restrict__ out, int K, int N)
{
    __shared__ float t[32][33];
    const size_t l = blockIdx.z;
    in  += l * (size_t)K * N;
    out += l * (size_t)K * N;
    int n0 = blockIdx.x * 32, k0 = blockIdx.y * 32;
    int tx = threadIdx.x & 31, ty = threadIdx.x >> 5;    // 32 x 8
    #pragma unroll
    for (int r = 0; r < 32; r += 8)
        t[ty + r][tx] = in[(size_t)(k0 + ty + r) * N + n0 + tx];
    __syncthreads();
    #pragma unroll
    for (int r = 0; r < 32; r += 8)
        out[(size_t)(n0 + ty + r) * K + k0 + tx] = f2h(t[tx][ty + r]);
}

// ---------------------------------------------------------------------------
// fp16 MFMA GEMM, double-buffered LDS (2-phase: issue loads -> MFMA -> write).
// (unchanged from the verified round-3 kernel)
// ---------------------------------------------------------------------------
template<bool QKV, bool RELU, bool AHALF, bool OUTHF>
__global__ __launch_bounds__(256)
void gemm_mfma(const void* __restrict__ Ap,
               const short* __restrict__ W0, const short* __restrict__ W1,
               const short* __restrict__ W2,
               const float* __restrict__ b0, const float* __restrict__ b1,
               const float* __restrict__ b2,
               const float* __restrict__ resid,
               float* __restrict__ C0, float* __restrict__ C1,
               float* __restrict__ C2,
               short* __restrict__ Chf,
               int M, int N, int K, float scale)
{
    __shared__ short As[2][64 * 32];   // [buf][m][k] fp16
    __shared__ short Bs[2][64 * 32];   // [buf][n][k] fp16

    const int bm = blockIdx.y * 64;
    int bn = blockIdx.x * 64;
    int sel = 0;
    if (QKV) { sel = bn >> 8; bn &= 255; }
    const short* Wt   = QKV ? (sel == 0 ? W0 : (sel == 1 ? W1 : W2)) : W0;
    const float* bias = QKV ? (sel == 0 ? b0 : (sel == 1 ? b1 : b2)) : b0;
    float*       C    = QKV ? (sel == 0 ? C0 : (sel == 1 ? C1 : C2)) : C0;
    const float  scl  = (QKV && sel > 0) ? 1.f : scale;
    const int    ldc  = QKV ? 256 : N;

    const int tid  = threadIdx.x;
    const int row  = tid >> 2;            // 0..63 (staging row)
    const int kq   = (tid & 3) * 8;       // 0,8,16,24
    const int wid  = tid >> 6, lane = tid & 63;
    const int wm   = wid >> 1, wn = wid & 1;
    const int lr   = lane & 15, lk = (lane >> 4) * 8;

    const float* Af = (const float*)Ap;
    const short* Ah = (const short*)Ap;
    const size_t aoff = (size_t)(bm + row) * K + kq;   // + k0
    const size_t boff = (size_t)(bn + row) * K + kq;   // + k0
    const int    lofs = row * 32 + kq;

    f32x4 acc00 = {0.f, 0.f, 0.f, 0.f};
    f32x4 acc01 = acc00, acc10 = acc00, acc11 = acc00;

    // prologue: stage tile 0 into buffer 0
    {
        s16x8 ha;
        if (AHALF) {
            ha = *(const s16x8*)&Ah[aoff];
        } else {
            float4 p0 = *(const float4*)&Af[aoff];
            float4 p1 = *(const float4*)&Af[aoff + 4];
            ha[0] = f2h(p0.x); ha[1] = f2h(p0.y); ha[2] = f2h(p0.z); ha[3] = f2h(p0.w);
            ha[4] = f2h(p1.x); ha[5] = f2h(p1.y); ha[6] = f2h(p1.z); ha[7] = f2h(p1.w);
        }
        *(s16x8*)&As[0][lofs] = ha;
        *(s16x8*)&Bs[0][lofs] = *(const s16x8*)&Wt[boff];
    }

    const int nt = K >> 5;
    for (int t = 0; t < nt; ++t) {
        const int buf = t & 1;
        __syncthreads();                  // staged buf visible; buf^1 free
        float4 p0, p1; s16x8 ha, hb;
        const bool pf = (t + 1 < nt);
        if (pf) {
            const int k0 = (t + 1) << 5;
            if (AHALF) {
                ha = *(const s16x8*)&Ah[aoff + k0];
            } else {
                p0 = *(const float4*)&Af[aoff + k0];
                p1 = *(const float4*)&Af[aoff + k0 + 4];
            }
            hb = *(const s16x8*)&Wt[boff + k0];
        }
        f16x8 a0 = *(const f16x8*)&As[buf][(wm * 32 + lr) * 32 + lk];
        f16x8 a1 = *(const f16x8*)&As[buf][(wm * 32 + 16 + lr) * 32 + lk];
        f16x8 v0 = *(const f16x8*)&Bs[buf][(wn * 32 + lr) * 32 + lk];
        f16x8 v1 = *(const f16x8*)&Bs[buf][(wn * 32 + 16 + lr) * 32 + lk];
        acc00 = __builtin_amdgcn_mfma_f32_16x16x32_f16(a0, v0, acc00, 0, 0, 0);
        acc01 = __builtin_amdgcn_mfma_f32_16x16x32_f16(a0, v1, acc01, 0, 0, 0);
        acc10 = __builtin_amdgcn_mfma_f32_16x16x32_f16(a1, v0, acc10, 0, 0, 0);
        acc11 = __builtin_amdgcn_mfma_f32_16x16x32_f16(a1, v1, acc11, 0, 0, 0);
        if (pf) {
            if (!AHALF) {
                ha[0] = f2h(p0.x); ha[1] = f2h(p0.y); ha[2] = f2h(p0.z); ha[3] = f2h(p0.w);
                ha[4] = f2h(p1.x); ha[5] = f2h(p1.y); ha[6] = f2h(p1.z); ha[7] = f2h(p1.w);
            }
            *(s16x8*)&As[buf ^ 1][lofs] = ha;
            *(s16x8*)&Bs[buf ^ 1][lofs] = hb;
        }
    }

    f32x4 accs[2][2] = {{acc00, acc01}, {acc10, acc11}};
    #pragma unroll
    for (int fm = 0; fm < 2; ++fm) {
        #pragma unroll
        for (int fn = 0; fn < 2; ++fn) {
            #pragma unroll
            for (int j = 0; j < 4; ++j) {
                int m = bm + wm * 32 + fm * 16 + (lane >> 4) * 4 + j;
                int n = bn + wn * 32 + fn * 16 + lr;
                float v = (accs[fm][fn][j] + bias[n]) * scl;
                if (resid) v += resid[(size_t)m * ldc + n];
                if (RELU)  v = fmaxf(v, 0.f);
                if (OUTHF) Chf[(size_t)m * ldc + n] = f2h(v);
                else       C[(size_t)m * ldc + n]   = v;
            }
        }
    }
}

// ---------------------------------------------------------------------------
// Fused structure-aware attention v5: v4c pipeline, spill-free.
//  - ps_r[40] per-thread accumulator ELIMINATED (it spilled under the VGPR
//    cap in v4c: WRITE_SIZE 1.37 GB/dispatch of scratch). Replaced by the
//    per-tile identity  sv[dk] = sum_dep (sum_k e_k st[k][dep]) Wsv[dep][dk]:
//      eps_s[h][dep] computed per tile (wave-synchronous within h-group),
//      folded into a SCALAR svacc per thread (40 MACs vs Wsv in LDS).
//  - plain __launch_bounds__(256): no forced occupancy -> no allocator cap.
//  - keeps: triple-buffer depth-2 structure prefetch, nontemporal streams,
//    XCD swizzle (batch == bid&7), deferred alpha-rescale.
// ---------------------------------------------------------------------------
__global__ __launch_bounds__(256)
void attn_kernel(const float* __restrict__ qb,   // [B,S,D] pre-scaled 1/sqrt(dk)
                 const float* __restrict__ kb,
                 const float* __restrict__ vb,
                 const float* __restrict__ structure, // [B,S,S,DEP]
                 const int*   __restrict__ mask,      // [B,S,S]
                 const int*   __restrict__ kpm,       // [B,S]
                 const float* __restrict__ Wsk, const float* __restrict__ bsk,
                 const float* __restrict__ Wsv, const float* __restrict__ bsv,
                 float* __restrict__ ctx)
{
    __shared__ float q_s[D_];
    __shared__ float wqk_s[H_][44];
    __shared__ float hb_s[H_];
    __shared__ float st_s[3][TK3][44];   // rows 16B-aligned (44*4=176)
    __shared__ float dead_s[3][TK3];     // additive 0 / -1e18
    __shared__ float sc_s[H_][TK3];
    __shared__ float wsv_s[DEP_ * DK_];  // [dep][dk], 5 KB
    __shared__ float eps_s[H_][DEP_];    // per-tile  sum_k e_k * st[k][dep]

    // XCD swizzle: consecutive blockIdx round-robin XCDs; make batch == bid&7
    const int b   = blockIdx.x & 7;
    const int qi  = blockIdx.x >> 3;
    const int tid = threadIdx.x;
    const int h    = tid >> 5;
    const int lane = tid & 31;

    q_s[tid] = qb[((size_t)b * S_ + qi) * D_ + tid];
    __syncthreads();

    for (int p = tid; p < H_ * DEP_; p += 256) {
        int hh = p / DEP_, dep = p - hh * DEP_;
        const float4* wr = (const float4*)(Wsk + dep * DK_);
        const float4* qr = (const float4*)(q_s + hh * DK_);
        float s = 0.f;
        #pragma unroll
        for (int c = 0; c < 8; ++c) s += dot4(qr[c], wr[c]);
        wqk_s[hh][dep] = s;
    }
    if (tid < H_) {
        const float4* qr = (const float4*)(q_s + tid * DK_);
        const float4* br = (const float4*)bsk;
        float s = 0.f;
        #pragma unroll
        for (int c = 0; c < 8; ++c) s += dot4(qr[c], br[c]);
        hb_s[tid] = s;
    }
    for (int p = tid; p < DEP_ * DK_; p += 256) wsv_s[p] = Wsv[p];
    __syncthreads();

    const float* kbase = kb + (size_t)b * S_ * D_;
    const float* vbase = vb + (size_t)b * S_ * D_ + tid;
    const float* strow = structure + (size_t)(b * S_ + qi) * S_ * DEP_;
    const int*   mrow  = mask + (size_t)(b * S_ + qi) * S_;
    const int*   krow  = kpm + (size_t)b * S_;

    // per-thread staging coordinates (320 float4-chunks per 32-key tile)
    const int kk0 = tid / 10, d40 = tid - kk0 * 10;         // chunk tid
    const int c1  = tid + 256;
    const int kk1 = c1 / 10,  d41 = c1 - kk1 * 10;          // chunk tid+256
    const bool has2 = (tid < 64);

    const int nt = S_ / TK3;   // 16

    // prologue: tile 0 -> LDS buf0 directly; tile 1 -> registers (r1)
    {
        *(f32x4*)&st_s[0][kk0][d40 * 4] =
            __builtin_nontemporal_load((const f32x4*)&strow[(size_t)kk0 * DEP_ + d40 * 4]);
        if (has2)
            *(f32x4*)&st_s[0][kk1][d41 * 4] =
                __builtin_nontemporal_load((const f32x4*)&strow[(size_t)kk1 * DEP_ + d41 * 4]);
        if (tid < TK3)
            dead_s[0][tid] =
                (__builtin_nontemporal_load(&mrow[tid]) == 0 || krow[tid] == 0) ? NEG_ : 0.f;
    }
    f32x4 r1a = {0.f, 0.f, 0.f, 0.f}, r1b = r1a;
    int m1 = 1, p1 = 1;
    {
        const float* s1 = strow + (size_t)TK3 * DEP_;
        r1a = __builtin_nontemporal_load((const f32x4*)&s1[(size_t)kk0 * DEP_ + d40 * 4]);
        if (has2) r1b = __builtin_nontemporal_load((const f32x4*)&s1[(size_t)kk1 * DEP_ + d41 * 4]);
        if (tid < TK3) { m1 = __builtin_nontemporal_load(&mrow[TK3 + tid]); p1 = krow[TK3 + tid]; }
    }

    float m_run = -INFINITY, l_run = 0.f, vacc = 0.f, svacc = 0.f;

    const float4* qp  = (const float4*)(q_s + h * DK_);
    const float4* wq4 = (const float4*)&wqk_s[h][0];

    for (int t = 0; t < nt; ++t) {
        const int buf = t % 3;
        const int k0  = t * TK3;
        __syncthreads();                 // buf (written last iter) now visible
        // issue tile t+2 loads into regs (HBM latency hides under 2 tiles)
        f32x4 r2a = {0.f, 0.f, 0.f, 0.f}, r2b = r2a;
        int m2 = 1, p2 = 1;
        if (t + 2 < nt) {
            const float* s2 = strow + (size_t)(t + 2) * TK3 * DEP_;
            r2a = __builtin_nontemporal_load((const f32x4*)&s2[(size_t)kk0 * DEP_ + d40 * 4]);
            if (has2) r2b = __builtin_nontemporal_load((const f32x4*)&s2[(size_t)kk1 * DEP_ + d41 * 4]);
            if (tid < TK3) {
                m2 = __builtin_nontemporal_load(&mrow[(t + 2) * TK3 + tid]);
                p2 = krow[(t + 2) * TK3 + tid];
            }
        }
        // write tile t+1 (loaded a full tile ago) into buffer (t+1)%3
        if (t + 1 < nt) {
            const int wb = (t + 1) % 3;
            *(f32x4*)&st_s[wb][kk0][d40 * 4] = r1a;
            if (has2) *(f32x4*)&st_s[wb][kk1][d41 * 4] = r1b;
            if (tid < TK3) dead_s[wb][tid] = (m1 == 0 || p1 == 0) ? NEG_ : 0.f;
        }
        // ---- compute tile t ----
        const int key = k0 + lane;
        const float4* kp = (const float4*)(kbase + (size_t)key * D_ + h * DK_);
        float kq = 0.f;
        #pragma unroll
        for (int c = 0; c < 8; ++c) kq += dot4(qp[c], kp[c]);
        const float4* sp = (const float4*)&st_s[buf][lane][0];
        float bias = hb_s[h];
        #pragma unroll
        for (int c = 0; c < 10; ++c) bias += dot4(sp[c], wq4[c]);
        float sc = kq + bias + dead_s[buf][lane];
        float tm = sc;
        #pragma unroll
        for (int off = 16; off; off >>= 1) tm = fmaxf(tm, __shfl_xor(tm, off));
        float m_new = fmaxf(m_run, tm);
        float e = __expf(sc - m_new);
        float psum = e;
        #pragma unroll
        for (int off = 16; off; off >>= 1) psum += __shfl_xor(psum, off);
        // deferred rescale: only 3 scalars now (l_run, vacc, svacc)
        if (m_new > m_run) {
            float alpha = __expf(m_run - m_new);
            l_run *= alpha;
            vacc  *= alpha;
            svacc *= alpha;
            m_run = m_new;
        }
        l_run += psum;
        sc_s[h][lane] = e;
        // eps[h][dep] = sum_k e_k * st[k][dep]  (wave-synchronous: written and
        // read by the same 32-lane h-group; sc_s likewise — no barrier needed)
        {
            float acc0 = 0.f;
            #pragma unroll 8
            for (int k = 0; k < TK3; ++k)
                acc0 += sc_s[h][k] * st_s[buf][k][lane];
            eps_s[h][lane] = acc0;
            if (lane < DEP_ - TK3) {     // deps 32..39
                float acc1 = 0.f;
                #pragma unroll 8
                for (int k = 0; k < TK3; ++k)
                    acc1 += sc_s[h][k] * st_s[buf][k][TK3 + lane];
                eps_s[h][TK3 + lane] = acc1;
            }
        }
        // svacc[dk=lane] += sum_dep eps[h][dep] * Wsv[dep][lane]
        {
            float sacc = 0.f;
            #pragma unroll 8
            for (int dep = 0; dep < DEP_; ++dep)
                sacc += eps_s[h][dep] * wsv_s[dep * DK_ + lane];
            svacc += sacc;
        }
        // phase D: ctx_v accumulate (thread as (h, dk=lane))
        #pragma unroll 8
        for (int k = 0; k < TK3; ++k) {
            vacc += sc_s[h][k] * vbase[(size_t)(k0 + k) * D_];
        }
        // rotate prefetch registers
        r1a = r2a; r1b = r2b; m1 = m2; p1 = p2;
    }

    float invl = 1.f / l_run;
    ctx[((size_t)b * S_ + qi) * D_ + tid] = (vacc + svacc) * invl + bsv[lane];
}

// ---------------------------------------------------------------------------
// LayerNorm over last dim (256). One block per row.
// ---------------------------------------------------------------------------
__global__ __launch_bounds__(256)
void ln_kernel(const float* __restrict__ x, const float* __restrict__ g,
               const float* __restrict__ b, float* __restrict__ out)
{
    int row = blockIdx.x, tid = threadIdx.x;
    float v = x[(size_t)row * D_ + tid];
    float s = v, ss = v * v;
    #pragma unroll
    for (int off = 32; off; off >>= 1) {
        s  += __shfl_xor(s, off);
        ss += __shfl_xor(ss, off);
    }
    __shared__ float rs[4], rss[4];
    int wid = tid >> 6, lane = tid & 63;
    if (lane == 0) { rs[wid] = s; rss[wid] = ss; }
    __syncthreads();
    float sum  = rs[0] + rs[1] + rs[2] + rs[3];
    float ssum = rss[0] + rss[1] + rss[2] + rss[3];
    float mean = sum * (1.f / D_);
    float var  = ssum * (1.f / D_) - mean * mean;
    out[(size_t)row * D_ + tid] = (v - mean) * rsqrtf(var + 1e-6f) * g[tid] + b[tid];
}

// ---------------------------------------------------------------------------
extern "C" void kernel_launch(void* const* d_in, const int* in_sizes, int n_in,
                              void* d_out, int out_size, void* d_ws, size_t ws_size,
                              hipStream_t stream)
{
    (void)in_sizes; (void)n_in; (void)out_size; (void)ws_size;
    const float* src       = (const float*)d_in[0];
    const int*   mask      = (const int*)  d_in[1];
    const int*   kpm       = (const int*)  d_in[2];
    const float* structure = (const float*)d_in[3];
    const float* Wq  = (const float*)d_in[4];  const float* bq  = (const float*)d_in[5];
    const float* Wk  = (const float*)d_in[6];  const float* bk  = (const float*)d_in[7];
    const float* Wv  = (const float*)d_in[8];  const float* bv  = (const float*)d_in[9];
    const float* Wo  = (const float*)d_in[10]; const float* bo  = (const float*)d_in[11];
    const float* Wsk = (const float*)d_in[12]; const float* bsk = (const float*)d_in[13];
    const float* Wsv = (const float*)d_in[14]; const float* bsv = (const float*)d_in[15];
    const float* ln1g = (const float*)d_in[16]; const float* ln1b = (const float*)d_in[17];
    const float* Wf1 = (const float*)d_in[18]; const float* bf1 = (const float*)d_in[19];
    const float* Wf2 = (const float*)d_in[20]; const float* bf2 = (const float*)d_in[21];
    const float* lnfg = (const float*)d_in[22]; const float* lnfb = (const float*)d_in[23];

    const int M = B_ * S_;                 // 4096
    const size_t NB = (size_t)M * D_;      // 1M floats = 4 MB
    float* ws   = (float*)d_ws;
    float* x    = ws;
    float* qb   = ws + 1 * NB;
    float* kb2  = ws + 2 * NB;
    float* vb2  = ws + 3 * NB;
    float* ctx  = ws + 4 * NB;
    float* outb = ws + 5 * NB;
    float* hln  = ws + 6 * NB;
    short* f1hf = (short*)(ws + 7 * NB);   // M x DFF fp16 = 8 MB (ends at 9*NB)
    short* wq_t  = (short*)(ws + 9 * NB);  // [L][D][D] fp16 (W^T per layer)
    short* wk_t  = wq_t  + (size_t)L_ * D_ * D_;
    short* wv_t  = wk_t  + (size_t)L_ * D_ * D_;
    short* wo_t  = wv_t  + (size_t)L_ * D_ * D_;
    short* wf1_t = wo_t  + (size_t)L_ * D_ * D_;    // [L][DFF][D]
    short* wf2_t = wf1_t + (size_t)L_ * D_ * DFF_;  // [L][D][DFF]

    copy_kernel<<<1024, 256, 0, stream>>>((const float4*)src, (float4*)x, (int)(NB / 4));

    // one-time (per call) weight transpose-convert to fp16 [N][K]
    wconv<<<dim3(D_ / 32, D_ / 32, L_), 256, 0, stream>>>(Wq, wq_t, D_, D_);
    wconv<<<dim3(D_ / 32, D_ / 32, L_), 256, 0, stream>>>(Wk, wk_t, D_, D_);
    wconv<<<dim3(D_ / 32, D_ / 32, L_), 256, 0, stream>>>(Wv, wv_t, D_, D_);
    wconv<<<dim3(D_ / 32, D_ / 32, L_), 256, 0, stream>>>(Wo, wo_t, D_, D_);
    wconv<<<dim3(DFF_ / 32, D_ / 32, L_), 256, 0, stream>>>(Wf1, wf1_t, D_, DFF_);
    wconv<<<dim3(D_ / 32, DFF_ / 32, L_), 256, 0, stream>>>(Wf2, wf2_t, DFF_, D_);

    const float qscale = 0.17677669529663689f; // 1/sqrt(32)
    for (int i = 0; i < L_; ++i) {
        const size_t od = (size_t)i * D_ * D_;
        const size_t of = (size_t)i * D_ * DFF_;
        // fused QKV (N=768 logical -> 3 separate [M,256] outputs)
        gemm_mfma<true, false, false, false><<<dim3(12, 64), 256, 0, stream>>>(
            x, wq_t + od, wk_t + od, wv_t + od,
            bq + i * D_, bk + i * D_, bv + i * D_, nullptr,
            qb, kb2, vb2, nullptr, M, 768, D_, qscale);
        attn_kernel<<<B_ * S_, 256, 0, stream>>>(
            qb, kb2, vb2, structure, mask, kpm,
            Wsk + (size_t)i * DEP_ * DK_, bsk + i * DK_,
            Wsv + (size_t)i * DEP_ * DK_, bsv + i * DK_, ctx);
        gemm_mfma<false, false, false, false><<<dim3(4, 64), 256, 0, stream>>>(
            ctx, wo_t + od, wo_t + od, wo_t + od,
            bo + i * D_, nullptr, nullptr, x,
            outb, nullptr, nullptr, nullptr, M, D_, D_, 1.f);
        ln_kernel<<<M, 256, 0, stream>>>(outb, ln1g + i * D_, ln1b + i * D_, hln);
        gemm_mfma<false, true, false, true><<<dim3(16, 64), 256, 0, stream>>>(
            hln, wf1_t + of, wf1_t + of, wf1_t + of,
            bf1 + i * DFF_, nullptr, nullptr, nullptr,
            nullptr, nullptr, nullptr, f1hf, M, DFF_, D_, 1.f);
        gemm_mfma<false, false, true, false><<<dim3(4, 64), 256, 0, stream>>>(
            f1hf, wf2_t + of, wf2_t + of, wf2_t + of,
            bf2 + i * D_, nullptr, nullptr, outb,
            x, nullptr, nullptr, nullptr, M, D_, DFF_, 1.f);
    }
    ln_kernel<<<M, 256, 0, stream>>>(x, lnfg, lnfb, (float*)d_out);
}